// Round 4
// baseline (124.269 us; speedup 1.0000x reference)
//
#include <hip/hip_runtime.h>

#define NQ 19
#define SZ (1u << NQ)

// ---------------------------------------------------------------------------
// Prep (1 block): GCN front-end in fp64 -> feats[19]; fused gate matrices
// G[6][19(bit)][4] fp32; phase-factor tables E0[1024] (bits 0..9, includes
// global -S/2 phase) and E1[512] (bits 10..18, includes 2^-9.5 amplitude).
// Qubit q <-> flat-index bit k = 18 - q. Fused 1q gate U = RZ(t)*RX(t).
// ---------------------------------------------------------------------------
__global__ __launch_bounds__(128)
void k_prep(const int* __restrict__ ei, const float* __restrict__ state,
            const float* __restrict__ mass, const float* __restrict__ spin,
            const float* __restrict__ charge, const float* __restrict__ p_norm,
            const float* __restrict__ theta,
            const float* __restrict__ gnw, const float* __restrict__ gnb,
            const float* __restrict__ gew, const float* __restrict__ geb,
            const float* __restrict__ nw, const float* __restrict__ nb,
            const float* __restrict__ ew, const float* __restrict__ eb,
            const float* __restrict__ qw,
            float2* __restrict__ G, float2* __restrict__ E0,
            float2* __restrict__ E1)
{
    __shared__ double feats[NQ];
    int tid = threadIdx.x;
    if (tid == 0) {
        double deg[8], dis[8], h[8], o1[8], he[8], o2[8];
        for (int v = 0; v < 8; ++v) deg[v] = 1.0;                 // self loops
        for (int e = 0; e < 8; ++e) deg[ei[8 + e]] += 1.0;
        for (int v = 0; v < 8; ++v) dis[v] = 1.0 / sqrt(deg[v]);
        for (int v = 0; v < 8; ++v) {
            double s = 0.0;
            for (int k = 0; k < 4; ++k) s += (double)state[v * 4 + k] * (double)gnw[k];
            h[v] = s;
        }
        for (int v = 0; v < 8; ++v) o1[v] = h[v] * dis[v] * dis[v] + (double)gnb[0];
        for (int e = 0; e < 8; ++e) {
            int s = ei[e], d = ei[8 + e];
            o1[d] += h[s] * dis[s] * dis[d];
        }
        for (int j = 0; j < 9; ++j) {
            double a = (double)nb[j];
            for (int v = 0; v < 8; ++v) a += o1[v] * (double)nw[v * 9 + j];
            feats[j] = a;
        }
        for (int e = 0; e < 8; ++e)
            he[e] = (double)mass[e] * (double)gew[0] + (double)spin[e] * (double)gew[1]
                  + (double)charge[e] * (double)gew[2];
        for (int v = 0; v < 8; ++v) o2[v] = he[v] * dis[v] * dis[v] + (double)geb[0];
        for (int e = 0; e < 8; ++e) {
            int s = ei[e], d = ei[8 + e];
            o2[d] += he[s] * dis[s] * dis[d];
        }
        for (int j = 0; j < 8; ++j) {
            double a = (double)eb[j];
            for (int v = 0; v < 8; ++v) a += o2[v] * (double)ew[v * 8 + j];
            feats[9 + j] = a;
        }
        feats[17] = (double)p_norm[0];
        feats[18] = (double)theta[0];
    }
    __syncthreads();
    for (int g = tid; g < 6 * NQ; g += blockDim.x) {
        int l = g / NQ, q = g % NQ;
        int i = l / 3, j = l % 3;
        double t = (double)qw[i * (NQ * 3) + q * 3 + j];
        double c = cos(0.5 * t), s = sin(0.5 * t);
        int k = 18 - q;
        float2* Ug = &G[(l * NQ + k) * 4];
        Ug[0] = make_float2((float)(c * c), (float)(-s * c));
        Ug[1] = make_float2((float)(-s * s), (float)(-c * s));
        Ug[2] = make_float2((float)(s * s), (float)(-c * s));
        Ug[3] = make_float2((float)(c * c), (float)(s * c));
    }
    double S = 0.0;
    for (int q = 0; q < NQ; ++q) S += feats[q];
    for (int m = tid; m < 1024; m += blockDim.x) {
        double a = -0.5 * S;
        for (int k = 0; k < 10; ++k)
            if ((m >> k) & 1) a += feats[18 - k];
        double sp, cp;
        sincos(a, &sp, &cp);
        E0[m] = make_float2((float)cp, (float)sp);
    }
    const double amp = 1.0 / sqrt((double)SZ);
    for (int m = tid; m < 512; m += blockDim.x) {
        double a = 0.0;
        for (int k = 0; k < 9; ++k)
            if ((m >> k) & 1) a += feats[8 - k];
        double sp, cp;
        sincos(a, &sp, &cp);
        E1[m] = make_float2((float)(amp * cp), (float)(amp * sp));
    }
}

// Ring permutation inverse (bit space):
//   b = (c ^ (c>>1)) & 0x1FFFF ; b17 = c0^c17^c18 ; b18 = c0^c18
// Bits >=10 of pinv(c) depend ONLY on c0 and c bits 10..18.
__device__ __forceinline__ unsigned pinv(unsigned c)
{
    unsigned y = (c ^ (c >> 1)) & 0x1FFFFu;
    unsigned c0 = c & 1u, c17 = (c >> 17) & 1u, c18 = (c >> 18) & 1u;
    return y | ((c0 ^ c17 ^ c18) << 17) | ((c0 ^ c18) << 18);
}

// Padded LDS index: +2 float2 per 8.
__device__ __forceinline__ unsigned padl(unsigned l) { return l + 2u * (l >> 3); }

__device__ __forceinline__ void bfly(float2& a, float2& b,
                                     float2 u00, float2 u01,
                                     float2 u10, float2 u11)
{
    float2 na, nb;
    na.x = u00.x * a.x - u00.y * a.y + u01.x * b.x - u01.y * b.y;
    na.y = u00.x * a.y + u00.y * a.x + u01.x * b.y + u01.y * b.x;
    nb.x = u10.x * a.x - u10.y * a.y + u11.x * b.x - u11.y * b.y;
    nb.y = u10.x * a.y + u10.y * a.x + u11.x * b.y + u11.y * b.x;
    a = na;
    b = nb;
}

// Apply n gates on amp bits ampbit0.., mapped to register-index bits jbit0..
__device__ __forceinline__ void apply_gates(float2 r[4], const float2* __restrict__ Gl,
                                            int ampbit0, int jbit0, int n)
{
    #pragma unroll
    for (int k = 0; k < n; ++k) {
        const float2 u00 = Gl[(ampbit0 + k) * 4 + 0];
        const float2 u01 = Gl[(ampbit0 + k) * 4 + 1];
        const float2 u10 = Gl[(ampbit0 + k) * 4 + 2];
        const float2 u11 = Gl[(ampbit0 + k) * 4 + 3];
        const int m = 1 << (jbit0 + k);
        #pragma unroll
        for (int j = 0; j < 4; ++j)
            if (!(j & m)) bfly(r[j], r[j | m], u00, u01, u10, u11);
    }
}

// ---------------------------------------------------------------------------
// Pass A: ring-gather (via coalesced 2-region LDS staging) + gates on c bits
// 0..9. 512 blocks x 256 threads, 4 amps/thread; block = c bits 10..18.
// Register layouts (tile index l, 10 bits):
//   P0: l=(t<<2)|j  P1: l=(t&3)|(j<<2)|((t>>2)<<4)  P2: (t&15)|(j<<4)|((t>>4)<<6)
//   P3: (t&63)|(j<<6)|((t>>6)<<8)                   P4: l=t|(j<<8)
// ---------------------------------------------------------------------------
__global__ __launch_bounds__(256)
void k_passA(const float2* __restrict__ in, float2* __restrict__ out,
             const float2* __restrict__ G, int layer,
             const float2* __restrict__ E0, const float2* __restrict__ E1,
             int first)
{
    __shared__ __align__(16) float2 Sstage[2560];
    __shared__ __align__(16) float2 X0[1280];
    __shared__ __align__(16) float2 X1[1280];
    const unsigned t = threadIdx.x;
    const unsigned base = blockIdx.x << 10;
    const float2* Gl = G + layer * NQ * 4;
    float2 r[4];

    if (first) {
        // stage E0[1024] then E1[512] (coalesced float4)
        #pragma unroll
        for (int k = 0; k < 2; ++k) {
            unsigned i = ((unsigned)k << 9) | (t << 1);
            float4 v = *reinterpret_cast<const float4*>(&E0[i]);
            *reinterpret_cast<float4*>(&Sstage[padl(i)]) = v;
        }
        {
            unsigned i = t << 1;
            float4 v = *reinterpret_cast<const float4*>(&E1[i]);
            *reinterpret_cast<float4*>(&Sstage[padl(1024u + i)]) = v;
        }
    } else {
        // the 2 contiguous source regions of this block's ring gather
        unsigned src0 = pinv(base) & ~1023u;
        unsigned src1 = pinv(base | 1u) & ~1023u;
        #pragma unroll
        for (int k = 0; k < 4; ++k) {
            unsigned i = ((unsigned)k << 9) | (t << 1);
            unsigned g = (i >= 1024u) ? (src1 + (i - 1024u)) : (src0 + i);
            float4 v = *reinterpret_cast<const float4*>(&in[g]);
            *reinterpret_cast<float4*>(&Sstage[padl(i)]) = v;
        }
    }
    __syncthreads();

    // gather (LDS permute) -> regs, j = c bits {0,1}
    #pragma unroll
    for (int j = 0; j < 4; ++j) {
        unsigned l = (t << 2) | (unsigned)j;
        unsigned c = base | l;
        unsigned b = pinv(c);
        if (first) {
            float2 e0 = Sstage[padl(b & 1023u)];
            float2 e1 = Sstage[padl(1024u + (b >> 10))];
            r[j] = make_float2(e0.x * e1.x - e0.y * e1.y,
                               e0.x * e1.y + e0.y * e1.x);
        } else {
            r[j] = Sstage[padl(((l & 1u) << 10) | (b & 1023u))];
        }
    }
    apply_gates(r, Gl, 0, 0, 2);

    // X: P0 -> P1
    #pragma unroll
    for (int jh = 0; jh < 2; ++jh)
        *reinterpret_cast<float4*>(&X0[padl((t << 2) | ((unsigned)jh << 1))]) =
            make_float4(r[2 * jh].x, r[2 * jh].y, r[2 * jh + 1].x, r[2 * jh + 1].y);
    __syncthreads();
    #pragma unroll
    for (int j = 0; j < 4; ++j)
        r[j] = X0[padl((t & 3u) | ((unsigned)j << 2) | ((t >> 2) << 4))];
    apply_gates(r, Gl, 2, 0, 2);

    // X: P1 -> P2
    #pragma unroll
    for (int j = 0; j < 4; ++j)
        X1[padl((t & 3u) | ((unsigned)j << 2) | ((t >> 2) << 4))] = r[j];
    __syncthreads();
    #pragma unroll
    for (int j = 0; j < 4; ++j)
        r[j] = X1[padl((t & 15u) | ((unsigned)j << 4) | ((t >> 4) << 6))];
    apply_gates(r, Gl, 4, 0, 2);

    // X: P2 -> P3
    #pragma unroll
    for (int j = 0; j < 4; ++j)
        X0[padl((t & 15u) | ((unsigned)j << 4) | ((t >> 4) << 6))] = r[j];
    __syncthreads();
    #pragma unroll
    for (int j = 0; j < 4; ++j)
        r[j] = X0[padl((t & 63u) | ((unsigned)j << 6) | ((t >> 6) << 8))];
    apply_gates(r, Gl, 6, 0, 2);

    // X: P3 -> P4
    #pragma unroll
    for (int j = 0; j < 4; ++j)
        X1[padl((t & 63u) | ((unsigned)j << 6) | ((t >> 6) << 8))] = r[j];
    __syncthreads();
    #pragma unroll
    for (int j = 0; j < 4; ++j)
        r[j] = X1[padl(t | ((unsigned)j << 8))];
    apply_gates(r, Gl, 8, 0, 2);

    // store (contiguous per j)
    #pragma unroll
    for (int j = 0; j < 4; ++j)
        out[base | t | ((unsigned)j << 8)] = r[j];
}

// ---------------------------------------------------------------------------
// Pass B: gates on c bits 10..18, in place. 512 blocks x 256 threads,
// 4 amps/thread; block = c bits 1..9; tile index l: l0=c0, l1..l9=c10..18.
//   c(l) = (l&1) | (blk<<1) | ((l>>1)<<10)
// Layouts: M0: l=(t&1)|(j<<1)|((t>>1)<<3)   M1: (t&7)|(j<<3)|((t>>3)<<5)
//          M2: (t&31)|(j<<5)|((t>>5)<<7)    M3: (t&127)|(j<<7)|((t>>7)<<9)
//          M4: l=t|(j<<8)   (gate c18 = l9 = j bit1)
// do_reduce (last layer): fold ring + <Z_0> into sign-twisted fp64 partials.
// ---------------------------------------------------------------------------
__global__ __launch_bounds__(256)
void k_passB(float2* __restrict__ buf, const float2* __restrict__ G, int layer,
             int do_reduce, double* __restrict__ partial)
{
    __shared__ __align__(16) float2 X0[1280];
    __shared__ __align__(16) float2 X1[1280];
    __shared__ double sm[256];
    const unsigned t = threadIdx.x;
    const unsigned blk = blockIdx.x;
    const float2* Gl = G + layer * NQ * 4;
    float2 r[4];

    // load @M0: j = c bits {10,11}
    #pragma unroll
    for (int j = 0; j < 4; ++j) {
        unsigned c = (t & 1u) | (blk << 1) | ((unsigned)j << 10) | ((t >> 1) << 12);
        r[j] = buf[c];
    }
    apply_gates(r, Gl, 10, 0, 2);

    // X: M0 -> M1
    #pragma unroll
    for (int j = 0; j < 4; ++j)
        X0[padl((t & 1u) | ((unsigned)j << 1) | ((t >> 1) << 3))] = r[j];
    __syncthreads();
    #pragma unroll
    for (int j = 0; j < 4; ++j)
        r[j] = X0[padl((t & 7u) | ((unsigned)j << 3) | ((t >> 3) << 5))];
    apply_gates(r, Gl, 12, 0, 2);

    // X: M1 -> M2
    #pragma unroll
    for (int j = 0; j < 4; ++j)
        X1[padl((t & 7u) | ((unsigned)j << 3) | ((t >> 3) << 5))] = r[j];
    __syncthreads();
    #pragma unroll
    for (int j = 0; j < 4; ++j)
        r[j] = X1[padl((t & 31u) | ((unsigned)j << 5) | ((t >> 5) << 7))];
    apply_gates(r, Gl, 14, 0, 2);

    // X: M2 -> M3
    #pragma unroll
    for (int j = 0; j < 4; ++j)
        X0[padl((t & 31u) | ((unsigned)j << 5) | ((t >> 5) << 7))] = r[j];
    __syncthreads();
    #pragma unroll
    for (int j = 0; j < 4; ++j)
        r[j] = X0[padl((t & 127u) | ((unsigned)j << 7) | ((t >> 7) << 9))];
    apply_gates(r, Gl, 16, 0, 2);

    // X: M3 -> M4
    #pragma unroll
    for (int j = 0; j < 4; ++j)
        X1[padl((t & 127u) | ((unsigned)j << 7) | ((t >> 7) << 9))] = r[j];
    __syncthreads();
    #pragma unroll
    for (int j = 0; j < 4; ++j)
        r[j] = X1[padl(t | ((unsigned)j << 8))];
    apply_gates(r, Gl, 18, 1, 1);     // gate c18 on j bit1

    if (do_reduce) {
        double acc = 0.0;
        #pragma unroll
        for (int j = 0; j < 4; ++j) {
            unsigned l = t | ((unsigned)j << 8);
            unsigned c = (l & 1u) | (blk << 1) | ((l >> 1) << 10);
            float2 v = r[j];
            double w = (double)v.x * v.x + (double)v.y * v.y;
            acc += (__popc(c & 0x3FFFFu) & 1) ? -w : w;
        }
        sm[t] = acc;
        __syncthreads();
        for (int st = 128; st > 0; st >>= 1) {
            if ((int)t < st) sm[t] += sm[t + st];
            __syncthreads();
        }
        if (t == 0) partial[blk] = sm[0];
    } else {
        #pragma unroll
        for (int j = 0; j < 4; ++j) {
            unsigned l = t | ((unsigned)j << 8);
            unsigned c = (l & 1u) | (blk << 1) | ((l >> 1) << 10);
            buf[c] = r[j];
        }
    }
}

__global__ __launch_bounds__(256)
void k_final(const double* __restrict__ partial, float* __restrict__ out)
{
    __shared__ double sm[256];
    sm[threadIdx.x] = partial[threadIdx.x] + partial[threadIdx.x + 256];
    __syncthreads();
    for (int st = 128; st > 0; st >>= 1) {
        if ((int)threadIdx.x < st) sm[threadIdx.x] += sm[threadIdx.x + st];
        __syncthreads();
    }
    if (threadIdx.x == 0) out[0] = (float)sm[0];
}

extern "C" void kernel_launch(void* const* d_in, const int* in_sizes, int n_in,
                              void* d_out, int out_size, void* d_ws, size_t ws_size,
                              hipStream_t stream)
{
    const int*   ei      = (const int*)d_in[0];
    const float* state   = (const float*)d_in[1];
    const float* mass    = (const float*)d_in[2];
    const float* spin    = (const float*)d_in[3];
    const float* charge  = (const float*)d_in[4];
    const float* p_norm  = (const float*)d_in[5];
    const float* theta   = (const float*)d_in[6];
    // d_in[7] = scattering (unused by reference)
    const float* gnw     = (const float*)d_in[8];
    const float* gnb     = (const float*)d_in[9];
    const float* gew     = (const float*)d_in[10];
    const float* geb     = (const float*)d_in[11];
    const float* nw      = (const float*)d_in[12];
    const float* nb      = (const float*)d_in[13];
    const float* ew      = (const float*)d_in[14];
    const float* eb      = (const float*)d_in[15];
    const float* qw      = (const float*)d_in[16];

    char* ws = (char*)d_ws;
    float2* G       = (float2*)(ws);                  // 6*19*4*8 = 3648 B
    float2* E0      = (float2*)(ws + 4096);           // 8 KiB
    float2* E1      = (float2*)(ws + 12288);          // 4 KiB
    double* partial = (double*)(ws + 16384);          // 4 KiB (512 doubles)
    float2* buf0    = (float2*)(ws + 32768);          // 4 MiB
    float2* buf1    = buf0 + SZ;                      // 4 MiB

    k_prep<<<1, 128, 0, stream>>>(ei, state, mass, spin, charge, p_norm, theta,
                                  gnw, gnb, gew, geb, nw, nb, ew, eb, qw,
                                  G, E0, E1);

    float2* bufs[2] = {buf0, buf1};
    for (int l = 0; l < 6; ++l) {
        float2* in  = bufs[l & 1];
        float2* out = bufs[(l & 1) ^ 1];
        k_passA<<<512, 256, 0, stream>>>(in, out, G, l, E0, E1, l == 0);
        k_passB<<<512, 256, 0, stream>>>(out, G, l, l == 5, partial);
    }
    k_final<<<1, 256, 0, stream>>>(partial, (float*)d_out);
}

// Round 5
// 100.578 us; speedup vs baseline: 1.2355x; 1.2355x over previous
//
#include <hip/hip_runtime.h>

#define NQ 19
#define SZ (1u << NQ)

// ---------------------------------------------------------------------------
// Prep (1 block): GCN front-end in fp64 -> feats[19]; fused gate matrices
// G[6][19(bit)][4] fp32; phase-factor tables E0[1024] (bits 0..9, includes
// global -S/2 phase) and E1[512] (bits 10..18, includes 2^-9.5 amplitude).
// Qubit q <-> flat-index bit k = 18 - q. Fused 1q gate U = RZ(t)*RX(t).
// ---------------------------------------------------------------------------
__global__ __launch_bounds__(128)
void k_prep(const int* __restrict__ ei, const float* __restrict__ state,
            const float* __restrict__ mass, const float* __restrict__ spin,
            const float* __restrict__ charge, const float* __restrict__ p_norm,
            const float* __restrict__ theta,
            const float* __restrict__ gnw, const float* __restrict__ gnb,
            const float* __restrict__ gew, const float* __restrict__ geb,
            const float* __restrict__ nw, const float* __restrict__ nb,
            const float* __restrict__ ew, const float* __restrict__ eb,
            const float* __restrict__ qw,
            float2* __restrict__ G, float2* __restrict__ E0,
            float2* __restrict__ E1)
{
    __shared__ double feats[NQ];
    int tid = threadIdx.x;
    if (tid == 0) {
        double deg[8], dis[8], h[8], o1[8], he[8], o2[8];
        for (int v = 0; v < 8; ++v) deg[v] = 1.0;                 // self loops
        for (int e = 0; e < 8; ++e) deg[ei[8 + e]] += 1.0;
        for (int v = 0; v < 8; ++v) dis[v] = 1.0 / sqrt(deg[v]);
        for (int v = 0; v < 8; ++v) {
            double s = 0.0;
            for (int k = 0; k < 4; ++k) s += (double)state[v * 4 + k] * (double)gnw[k];
            h[v] = s;
        }
        for (int v = 0; v < 8; ++v) o1[v] = h[v] * dis[v] * dis[v] + (double)gnb[0];
        for (int e = 0; e < 8; ++e) {
            int s = ei[e], d = ei[8 + e];
            o1[d] += h[s] * dis[s] * dis[d];
        }
        for (int j = 0; j < 9; ++j) {
            double a = (double)nb[j];
            for (int v = 0; v < 8; ++v) a += o1[v] * (double)nw[v * 9 + j];
            feats[j] = a;
        }
        for (int e = 0; e < 8; ++e)
            he[e] = (double)mass[e] * (double)gew[0] + (double)spin[e] * (double)gew[1]
                  + (double)charge[e] * (double)gew[2];
        for (int v = 0; v < 8; ++v) o2[v] = he[v] * dis[v] * dis[v] + (double)geb[0];
        for (int e = 0; e < 8; ++e) {
            int s = ei[e], d = ei[8 + e];
            o2[d] += he[s] * dis[s] * dis[d];
        }
        for (int j = 0; j < 8; ++j) {
            double a = (double)eb[j];
            for (int v = 0; v < 8; ++v) a += o2[v] * (double)ew[v * 8 + j];
            feats[9 + j] = a;
        }
        feats[17] = (double)p_norm[0];
        feats[18] = (double)theta[0];
    }
    __syncthreads();
    for (int g = tid; g < 6 * NQ; g += blockDim.x) {
        int l = g / NQ, q = g % NQ;
        int i = l / 3, j = l % 3;
        double t = (double)qw[i * (NQ * 3) + q * 3 + j];
        double c = cos(0.5 * t), s = sin(0.5 * t);
        int k = 18 - q;
        float2* Ug = &G[(l * NQ + k) * 4];
        Ug[0] = make_float2((float)(c * c), (float)(-s * c));
        Ug[1] = make_float2((float)(-s * s), (float)(-c * s));
        Ug[2] = make_float2((float)(s * s), (float)(-c * s));
        Ug[3] = make_float2((float)(c * c), (float)(s * c));
    }
    double S = 0.0;
    for (int q = 0; q < NQ; ++q) S += feats[q];
    for (int m = tid; m < 1024; m += blockDim.x) {
        double a = -0.5 * S;
        for (int k = 0; k < 10; ++k)
            if ((m >> k) & 1) a += feats[18 - k];
        double sp, cp;
        sincos(a, &sp, &cp);
        E0[m] = make_float2((float)cp, (float)sp);
    }
    const double amp = 1.0 / sqrt((double)SZ);
    for (int m = tid; m < 512; m += blockDim.x) {
        double a = 0.0;
        for (int k = 0; k < 9; ++k)
            if ((m >> k) & 1) a += feats[8 - k];
        double sp, cp;
        sincos(a, &sp, &cp);
        E1[m] = make_float2((float)(amp * cp), (float)(amp * sp));
    }
}

// Ring permutation inverse (bit space):
//   b = (c ^ (c>>1)) & 0x1FFFF ; b17 = c0^c17^c18 ; b18 = c0^c18
// Bits >=11 of pinv(c) depend ONLY on c0 and c bits 11..18.
__device__ __forceinline__ unsigned pinv(unsigned c)
{
    unsigned y = (c ^ (c >> 1)) & 0x1FFFFu;
    unsigned c0 = c & 1u, c17 = (c >> 17) & 1u, c18 = (c >> 18) & 1u;
    return y | ((c0 ^ c17 ^ c18) << 17) | ((c0 ^ c18) << 18);
}

// Padded LDS index: +2 float2 per 8 (keeps 8-groups intact; float4-safe).
__device__ __forceinline__ unsigned padl(unsigned l) { return l + 2u * (l >> 3); }

__device__ __forceinline__ void bfly(float2& a, float2& b,
                                     float2 u00, float2 u01,
                                     float2 u10, float2 u11)
{
    float2 na, nb;
    na.x = u00.x * a.x - u00.y * a.y + u01.x * b.x - u01.y * b.y;
    na.y = u00.x * a.y + u00.y * a.x + u01.x * b.y + u01.y * b.x;
    nb.x = u10.x * a.x - u10.y * a.y + u11.x * b.x - u11.y * b.y;
    nb.y = u10.x * a.y + u10.y * a.x + u11.x * b.y + u11.y * b.x;
    a = na;
    b = nb;
}

// Apply n gates on amp bits ampbit0.., mapped to register-index bits jbit0..
__device__ __forceinline__ void apply_gates(float2 r[4], const float2* __restrict__ Gl,
                                            int ampbit0, int jbit0, int n)
{
    #pragma unroll
    for (int k = 0; k < n; ++k) {
        const float2 u00 = Gl[(ampbit0 + k) * 4 + 0];
        const float2 u01 = Gl[(ampbit0 + k) * 4 + 1];
        const float2 u10 = Gl[(ampbit0 + k) * 4 + 2];
        const float2 u11 = Gl[(ampbit0 + k) * 4 + 3];
        const int m = 1 << (jbit0 + k);
        #pragma unroll
        for (int j = 0; j < 4; ++j)
            if (!(j & m)) bfly(r[j], r[j | m], u00, u01, u10, u11);
    }
}

// ---------------------------------------------------------------------------
// Pass A: ring-gather + gates on c bits 0..10 (11 gates, 6 phases).
// 256 blocks x 512 threads, tile = c bits 0..10 (2048 amps), block = c11..18.
// Gather: the tile's pre-ring sources form 2 contiguous 2048-amp regions
// (one per c0) -> coalesced float4 staging, then LDS permute.
// Register layouts (tile index l, 11 bits; j = 2 bits):
//   P0: l=(t<<2)|j              P1: (t&3)|(j<<2)|((t>>2)<<4)
//   P2: (t&15)|(j<<4)|((t>>4)<<6)  P3: (t&63)|(j<<6)|((t>>6)<<8)
//   P4: (t&255)|(j<<8)|((t>>8)<<10)  P5: t|(j<<9)
// ---------------------------------------------------------------------------
__global__ __launch_bounds__(512)
void k_passA(const float2* __restrict__ in, float2* __restrict__ out,
             const float2* __restrict__ G, int layer,
             const float2* __restrict__ E0, const float2* __restrict__ E1,
             int first)
{
    __shared__ __align__(16) float2 stage[5120];
    __shared__ __align__(16) float2 X0[2560];
    __shared__ __align__(16) float2 X1[2560];
    const unsigned t = threadIdx.x;
    const unsigned base = blockIdx.x << 11;
    const float2* Gl = G + layer * NQ * 4;
    float2 r[4];

    if (first) {
        {   // stage E0[1024]
            unsigned i = t << 1;
            if (i < 1024u)
                *reinterpret_cast<float4*>(&stage[padl(i)]) =
                    *reinterpret_cast<const float4*>(&E0[i]);
        }
        if (t < 256u) {  // stage E1[512] at slots 2048..2559
            unsigned i = t << 1;
            *reinterpret_cast<float4*>(&stage[padl(2048u + i)]) =
                *reinterpret_cast<const float4*>(&E1[i]);
        }
    } else {
        const unsigned R0 = pinv(base) & ~2047u;
        const unsigned R1 = pinv(base | 1u) & ~2047u;
        #pragma unroll
        for (int k = 0; k < 4; ++k) {
            unsigned i = ((unsigned)k << 10) | (t << 1);
            unsigned g = (i < 2048u) ? (R0 + i) : (R1 + (i - 2048u));
            *reinterpret_cast<float4*>(&stage[padl(i)]) =
                *reinterpret_cast<const float4*>(&in[g]);
        }
    }
    __syncthreads();

    // P0 gather-permute: j = c bits {0,1}
    #pragma unroll
    for (int j = 0; j < 4; ++j) {
        unsigned l = (t << 2) | (unsigned)j;
        unsigned b = pinv(base | l);
        if (first) {
            float2 e0 = stage[padl(b & 1023u)];
            float2 e1 = stage[padl(2048u + (b >> 10))];
            r[j] = make_float2(e0.x * e1.x - e0.y * e1.y,
                               e0.x * e1.y + e0.y * e1.x);
        } else {
            r[j] = stage[padl(((l & 1u) << 11) | (b & 2047u))];
        }
    }
    apply_gates(r, Gl, 0, 0, 2);

    // P0 -> P1 (X0)
    *reinterpret_cast<float4*>(&X0[padl(t << 2)]) =
        make_float4(r[0].x, r[0].y, r[1].x, r[1].y);
    *reinterpret_cast<float4*>(&X0[padl((t << 2) + 2u)]) =
        make_float4(r[2].x, r[2].y, r[3].x, r[3].y);
    __syncthreads();
    #pragma unroll
    for (int j = 0; j < 4; ++j)
        r[j] = X0[padl((t & 3u) | ((unsigned)j << 2) | ((t >> 2) << 4))];
    apply_gates(r, Gl, 2, 0, 2);

    // P1 -> P2 (X1)
    #pragma unroll
    for (int j = 0; j < 4; ++j)
        X1[padl((t & 3u) | ((unsigned)j << 2) | ((t >> 2) << 4))] = r[j];
    __syncthreads();
    #pragma unroll
    for (int j = 0; j < 4; ++j)
        r[j] = X1[padl((t & 15u) | ((unsigned)j << 4) | ((t >> 4) << 6))];
    apply_gates(r, Gl, 4, 0, 2);

    // P2 -> P3 (X0)
    #pragma unroll
    for (int j = 0; j < 4; ++j)
        X0[padl((t & 15u) | ((unsigned)j << 4) | ((t >> 4) << 6))] = r[j];
    __syncthreads();
    #pragma unroll
    for (int j = 0; j < 4; ++j)
        r[j] = X0[padl((t & 63u) | ((unsigned)j << 6) | ((t >> 6) << 8))];
    apply_gates(r, Gl, 6, 0, 2);

    // P3 -> P4 (X1)
    #pragma unroll
    for (int j = 0; j < 4; ++j)
        X1[padl((t & 63u) | ((unsigned)j << 6) | ((t >> 6) << 8))] = r[j];
    __syncthreads();
    #pragma unroll
    for (int j = 0; j < 4; ++j)
        r[j] = X1[padl((t & 255u) | ((unsigned)j << 8) | ((t >> 8) << 10))];
    apply_gates(r, Gl, 8, 0, 2);

    // P4 -> P5 (X0)
    #pragma unroll
    for (int j = 0; j < 4; ++j)
        X0[padl((t & 255u) | ((unsigned)j << 8) | ((t >> 8) << 10))] = r[j];
    __syncthreads();
    #pragma unroll
    for (int j = 0; j < 4; ++j)
        r[j] = X0[padl(t | ((unsigned)j << 9))];
    apply_gates(r, Gl, 10, 1, 1);          // gate c10 = l10 = j bit1

    // store: contiguous per j (512 consecutive float2 per wavefront set)
    #pragma unroll
    for (int j = 0; j < 4; ++j)
        out[base | t | ((unsigned)j << 9)] = r[j];
}

// ---------------------------------------------------------------------------
// Pass B: gates on c bits 11..18 (8 gates, 4 phases), in place.
// 256 blocks x 512 threads; tile l (11 bits): l0..l2 = c0..c2,
// l3..l10 = c11..c18; block = c bits 3..10.
//   c(l) = (l&7) | (blk<<3) | ((l>>3)<<11)      -> 64B contiguous runs.
// Layouts: M0: l=(t&7)|(j<<3)|((t>>3)<<5)   M1: (t&31)|(j<<5)|((t>>5)<<7)
//          M2: (t&127)|(j<<7)|((t>>7)<<9)   M3: l=t|(j<<9)
// do_reduce (last layer): fold final ring + <Z_0> into sign-twisted fp64
// partials: <Z_0> = sum_c (-1)^{popc(c&0x3FFFF)} |psi(c)|^2.
// ---------------------------------------------------------------------------
__global__ __launch_bounds__(512)
void k_passB(float2* __restrict__ buf, const float2* __restrict__ G, int layer,
             int do_reduce, double* __restrict__ partial)
{
    __shared__ __align__(16) float2 X0[2560];
    __shared__ __align__(16) float2 X1[2560];
    __shared__ double sm[512];
    const unsigned t = threadIdx.x;
    const unsigned blk = blockIdx.x;
    const float2* Gl = G + layer * NQ * 4;
    float2 r[4];

    // load @M0: j = c bits {11,12}
    #pragma unroll
    for (int j = 0; j < 4; ++j) {
        unsigned l = (t & 7u) | ((unsigned)j << 3) | ((t >> 3) << 5);
        unsigned c = (l & 7u) | (blk << 3) | ((l >> 3) << 11);
        r[j] = buf[c];
    }
    apply_gates(r, Gl, 11, 0, 2);

    // M0 -> M1 (X0)
    #pragma unroll
    for (int j = 0; j < 4; ++j)
        X0[padl((t & 7u) | ((unsigned)j << 3) | ((t >> 3) << 5))] = r[j];
    __syncthreads();
    #pragma unroll
    for (int j = 0; j < 4; ++j)
        r[j] = X0[padl((t & 31u) | ((unsigned)j << 5) | ((t >> 5) << 7))];
    apply_gates(r, Gl, 13, 0, 2);

    // M1 -> M2 (X1)
    #pragma unroll
    for (int j = 0; j < 4; ++j)
        X1[padl((t & 31u) | ((unsigned)j << 5) | ((t >> 5) << 7))] = r[j];
    __syncthreads();
    #pragma unroll
    for (int j = 0; j < 4; ++j)
        r[j] = X1[padl((t & 127u) | ((unsigned)j << 7) | ((t >> 7) << 9))];
    apply_gates(r, Gl, 15, 0, 2);

    // M2 -> M3 (X0)
    #pragma unroll
    for (int j = 0; j < 4; ++j)
        X0[padl((t & 127u) | ((unsigned)j << 7) | ((t >> 7) << 9))] = r[j];
    __syncthreads();
    #pragma unroll
    for (int j = 0; j < 4; ++j)
        r[j] = X0[padl(t | ((unsigned)j << 9))];
    apply_gates(r, Gl, 17, 0, 2);          // gates c17,c18 = l9,l10 = j bits

    if (do_reduce) {
        double acc = 0.0;
        #pragma unroll
        for (int j = 0; j < 4; ++j) {
            unsigned l = t | ((unsigned)j << 9);
            unsigned c = (l & 7u) | (blk << 3) | ((l >> 3) << 11);
            float2 v = r[j];
            double w = (double)v.x * v.x + (double)v.y * v.y;
            acc += (__popc(c & 0x3FFFFu) & 1) ? -w : w;
        }
        sm[t] = acc;
        __syncthreads();
        for (int st = 256; st > 0; st >>= 1) {
            if ((int)t < st) sm[t] += sm[t + st];
            __syncthreads();
        }
        if (t == 0) partial[blk] = sm[0];
    } else {
        #pragma unroll
        for (int j = 0; j < 4; ++j) {
            unsigned l = t | ((unsigned)j << 9);
            unsigned c = (l & 7u) | (blk << 3) | ((l >> 3) << 11);
            buf[c] = r[j];
        }
    }
}

__global__ __launch_bounds__(256)
void k_final(const double* __restrict__ partial, float* __restrict__ out)
{
    __shared__ double sm[256];
    sm[threadIdx.x] = partial[threadIdx.x];
    __syncthreads();
    for (int st = 128; st > 0; st >>= 1) {
        if ((int)threadIdx.x < st) sm[threadIdx.x] += sm[threadIdx.x + st];
        __syncthreads();
    }
    if (threadIdx.x == 0) out[0] = (float)sm[0];
}

extern "C" void kernel_launch(void* const* d_in, const int* in_sizes, int n_in,
                              void* d_out, int out_size, void* d_ws, size_t ws_size,
                              hipStream_t stream)
{
    const int*   ei      = (const int*)d_in[0];
    const float* state   = (const float*)d_in[1];
    const float* mass    = (const float*)d_in[2];
    const float* spin    = (const float*)d_in[3];
    const float* charge  = (const float*)d_in[4];
    const float* p_norm  = (const float*)d_in[5];
    const float* theta   = (const float*)d_in[6];
    // d_in[7] = scattering (unused by reference)
    const float* gnw     = (const float*)d_in[8];
    const float* gnb     = (const float*)d_in[9];
    const float* gew     = (const float*)d_in[10];
    const float* geb     = (const float*)d_in[11];
    const float* nw      = (const float*)d_in[12];
    const float* nb      = (const float*)d_in[13];
    const float* ew      = (const float*)d_in[14];
    const float* eb      = (const float*)d_in[15];
    const float* qw      = (const float*)d_in[16];

    char* ws = (char*)d_ws;
    float2* G       = (float2*)(ws);                  // 6*19*4*8 = 3648 B
    float2* E0      = (float2*)(ws + 4096);           // 8 KiB
    float2* E1      = (float2*)(ws + 12288);          // 4 KiB
    double* partial = (double*)(ws + 16384);          // 2 KiB (256 doubles)
    float2* buf0    = (float2*)(ws + 32768);          // 4 MiB
    float2* buf1    = buf0 + SZ;                      // 4 MiB

    k_prep<<<1, 128, 0, stream>>>(ei, state, mass, spin, charge, p_norm, theta,
                                  gnw, gnb, gew, geb, nw, nb, ew, eb, qw,
                                  G, E0, E1);

    float2* bufs[2] = {buf0, buf1};
    for (int l = 0; l < 6; ++l) {
        float2* in  = bufs[l & 1];
        float2* out = bufs[(l & 1) ^ 1];
        k_passA<<<256, 512, 0, stream>>>(in, out, G, l, E0, E1, l == 0);
        k_passB<<<256, 512, 0, stream>>>(out, G, l, l == 5, partial);
    }
    k_final<<<1, 256, 0, stream>>>(partial, (float*)d_out);
}